// Round 2
// baseline (240.811 us; speedup 1.0000x reference)
//
#include <hip/hip_runtime.h>

typedef unsigned int u32;

#define NPS   (256 * 1 * 128 * 128)   // elements per sample = T*C*H*W = 4194304
#define NSAMP 8
#define NB    2048                    // value-histogram buckets
#define PREDN 16384                   // H*W
#define BPS   256                     // blocks per sample in main pass
#define CHUNK (NPS / BPS)             // 16384 elements per block
#define NV4   (CHUNK / 4)             // 4096 float4 per block

// ---------------- impute: pred[h][w] = MLP(x_emb[h] * y_emb[w]) ----------------
__global__ __launch_bounds__(256) void impute_kernel(
    const float* __restrict__ xe, const float* __restrict__ ye,
    const float* __restrict__ w1, const float* __restrict__ b1,
    const float* __restrict__ w2, const float* __restrict__ b2,
    float* __restrict__ pred)
{
    __shared__ float sw1[64 * 32];
    __shared__ float sb1[32];
    __shared__ float sw2[32];
    __shared__ float sb2;
    for (int i = threadIdx.x; i < 2048; i += 256) sw1[i] = w1[i];
    if (threadIdx.x < 32) { sb1[threadIdx.x] = b1[threadIdx.x]; sw2[threadIdx.x] = w2[threadIdx.x]; }
    if (threadIdx.x == 0) sb2 = b2[0];
    __syncthreads();

    int t = blockIdx.x * 256 + threadIdx.x;
    if (t >= PREDN) return;
    int h = t >> 7, w = t & 127;

    float acc[32];
#pragma unroll
    for (int j = 0; j < 32; ++j) acc[j] = sb1[j];

    const float* xr = xe + h * 64;
    const float* yr = ye + w * 64;
#pragma unroll 4
    for (int e = 0; e < 64; ++e) {
        float p = xr[e] * yr[e];
#pragma unroll
        for (int j = 0; j < 32; ++j) acc[j] = fmaf(p, sw1[e * 32 + j], acc[j]);
    }
    float o = sb2;
#pragma unroll
    for (int j = 0; j < 32; ++j) {
        float a = acc[j];
        float s = a / (1.0f + expf(-a));   // silu
        o = fmaf(s, sw2[j], o);
    }
    pred[t] = o;
}

// ---------------- main pass: per-sample value histogram {count, sum residual^2} ----------------
__global__ __launch_bounds__(256) void main_pass(
    const float* __restrict__ data, const float* __restrict__ mask,
    const float* __restrict__ rnd, const float* __restrict__ pred,
    u32* __restrict__ hist_cnt, float* __restrict__ hist_sum,
    u32* __restrict__ zc, float* __restrict__ zs)
{
    __shared__ u32   lc[NB];
    __shared__ float ls[NB];
    for (int i = threadIdx.x; i < NB; i += 256) { lc[i] = 0u; ls[i] = 0.0f; }
    __syncthreads();

    const int s = blockIdx.y;
    const int start = blockIdx.x * CHUNK;
    const size_t base = (size_t)s * NPS + start;

    const float4* __restrict__ d4 = (const float4*)(data + base);
    const float4* __restrict__ m4 = (const float4*)(mask + base);
    const float4* __restrict__ r4 = (const float4*)(rnd + base);

    u32 lzc = 0; float lzs = 0.0f;

    // 16 float4 per thread; process in 4 groups of 4, loads batched per group
    // so 12 independent float4 loads are in flight before any use.
#pragma unroll
    for (int g = 0; g < 4; ++g) {
        const int v0 = g * 1024 + threadIdx.x;
        float4 dd[4], mm[4], rr[4];
#pragma unroll
        for (int u = 0; u < 4; ++u) {
            dd[u] = d4[v0 + u * 256];
            mm[u] = m4[v0 + u * 256];
            rr[u] = r4[v0 + u * 256];
        }
#pragma unroll
        for (int u = 0; u < 4; ++u) {
            const int e0 = start + (v0 + u * 256) * 4;
#pragma unroll
            for (int j = 0; j < 4; ++j) {
                float m = (&mm[u].x)[j];
                if (m != 0.0f) {
                    float rm = (&rr[u].x)[j] * m;
                    float resid = (&dd[u].x)[j] - pred[(e0 + j) & (PREDN - 1)];
                    float r2 = resid * resid;
                    if (rm > 0.0f) {
                        int b = (int)(rm * (float)NB);
                        b = b < NB ? b : NB - 1;
                        atomicAdd(&lc[b], 1u);
#if defined(__HIP_DEVICE_COMPILE__)
                        unsafeAtomicAdd(&ls[b], r2);
#else
                        atomicAdd(&ls[b], r2);
#endif
                    } else { lzc++; lzs += r2; }
                }
            }
        }
    }
    if (lzc) {
        atomicAdd(&zc[s], lzc);
#if defined(__HIP_DEVICE_COMPILE__)
        unsafeAtomicAdd(&zs[s], lzs);
#else
        atomicAdd(&zs[s], lzs);
#endif
    }
    __syncthreads();

    u32*   gc = hist_cnt + s * NB;
    float* gs = hist_sum + s * NB;
    for (int i = threadIdx.x; i < NB; i += 256) {
        u32 c = lc[i];
        if (c) {
            atomicAdd(&gc[i], c);
#if defined(__HIP_DEVICE_COMPILE__)
            unsafeAtomicAdd(&gs[i], ls[i]);
#else
            atomicAdd(&gs[i], ls[i]);
#endif
        }
    }
}

// ---------------- per-sample top-k selection over histogram ----------------
__global__ __launch_bounds__(256) void select_kernel(
    const u32* __restrict__ hist_cnt, const float* __restrict__ hist_sum,
    const u32* __restrict__ zc, const float* __restrict__ zs,
    double* __restrict__ psum, double* __restrict__ pcnt)
{
    const int s = blockIdx.x;
    __shared__ u32   lc[NB];
    __shared__ float ls[NB];
    __shared__ u32   tcnt[256];
    __shared__ float tsum[256];

    const u32*   gc = hist_cnt + s * NB;
    const float* gs = hist_sum + s * NB;
    for (int i = threadIdx.x; i < NB; i += 256) { lc[i] = gc[i]; ls[i] = gs[i]; }
    __syncthreads();

    {   // per-thread chunk of 8 consecutive buckets
        int t = threadIdx.x;
        u32 c = 0; float sm = 0.0f;
#pragma unroll
        for (int i = 0; i < NB / 256; ++i) { c += lc[t * (NB / 256) + i]; sm += ls[t * (NB / 256) + i]; }
        tcnt[t] = c; tsum[t] = sm;
    }
    __syncthreads();

    if (threadIdx.x == 0) {
        const int CPT = NB / 256;
        long long tot = 0;
        for (int t = 0; t < 256; ++t) tot += tcnt[t];
        long long zcs = (long long)zc[s];
        float nobs = (float)(tot + zcs);
        long long k = (long long)rintf(nobs * 0.1f);   // matches jnp.round (half-even)
        if (k > tot) k = tot;
        if (k < 0)  k = 0;

        double sel = 0.0; long long cum = 0; int tx = -1;
        for (int t = 255; t >= 0; --t) {
            u32 c = tcnt[t];
            if (cum + (long long)c <= k) { cum += c; sel += (double)tsum[t]; }
            else { tx = t; break; }
        }
        if (tx >= 0) {
            for (int b = tx * CPT + CPT - 1; b >= tx * CPT; --b) {
                u32 c = lc[b];
                if (cum + (long long)c <= k) { cum += c; sel += (double)ls[b]; }
                else {
                    long long need = k - cum;
                    if (need > 0) sel += (double)ls[b] * ((double)need / (double)c);
                    cum = k;
                    break;
                }
            }
        }
        psum[s] = sel + (double)zs[s];
        pcnt[s] = (double)(cum + zcs);
    }
}

__global__ void finalize_kernel(const double* __restrict__ psum,
                                const double* __restrict__ pcnt,
                                float* __restrict__ out)
{
    if (blockIdx.x == 0 && threadIdx.x == 0) {
        double S = 0.0, C = 0.0;
        for (int i = 0; i < NSAMP; ++i) { S += psum[i]; C += pcnt[i]; }
        out[0] = (float)(S / (C > 0.0 ? C : 1.0));
    }
}

extern "C" void kernel_launch(void* const* d_in, const int* in_sizes, int n_in,
                              void* d_out, int out_size, void* d_ws, size_t ws_size,
                              hipStream_t stream)
{
    const float* data = (const float*)d_in[0];
    const float* mask = (const float*)d_in[1];
    const float* rnd  = (const float*)d_in[4];
    const float* xe   = (const float*)d_in[5];
    const float* ye   = (const float*)d_in[6];
    const float* w1   = (const float*)d_in[7];
    const float* b1   = (const float*)d_in[8];
    const float* w2   = (const float*)d_in[9];
    const float* b2   = (const float*)d_in[10];
    float* out = (float*)d_out;

    char* ws = (char*)d_ws;
    float*  pred     = (float*)(ws);                         // 65536 B
    u32*    hist_cnt = (u32*)(ws + 65536);                   // NB*NSAMP*4 = 65536 B
    float*  hist_sum = (float*)(ws + 65536 + 65536);         // 65536 B
    u32*    zcp      = (u32*)(ws + 196608);                  // 32 B
    float*  zsp      = (float*)(ws + 196640);                // 32 B
    double* psum     = (double*)(ws + 196672);               // 64 B
    double* pcnt     = (double*)(ws + 196736);               // 64 B

    hipMemsetAsync(ws + 65536, 0, 131072 + 64, stream);

    impute_kernel<<<(PREDN + 255) / 256, 256, 0, stream>>>(xe, ye, w1, b1, w2, b2, pred);

    dim3 grid(BPS, NSAMP);
    main_pass<<<grid, 256, 0, stream>>>(data, mask, rnd, pred, hist_cnt, hist_sum, zcp, zsp);

    select_kernel<<<NSAMP, 256, 0, stream>>>(hist_cnt, hist_sum, zcp, zsp, psum, pcnt);
    finalize_kernel<<<1, 64, 0, stream>>>(psum, pcnt, out);
}

// Round 3
// 215.220 us; speedup vs baseline: 1.1189x; 1.1189x over previous
//
#include <hip/hip_runtime.h>

typedef unsigned int u32;

#define NPS   (256 * 1 * 128 * 128)   // elements per sample = 4194304
#define NSAMP 8
#define NB    2048                    // threshold-histogram buckets
#define PREDN 16384                   // H*W
#define BPS   256                     // blocks per sample in phase2
#define CHUNK (NPS / BPS)             // 16384 elements per block
#define ZONE  2                       // zone half-width in buckets

// acc layout per sample (8 u32 slots): 0 cnt_obs, 1 cnt_z, 2 cnt_hi, 3 cnt_x,
//                                      4 sum_z(f32), 5 sum_hi(f32), 6 sum_x(f32), 7 pad
#define ACC_STRIDE 8

// ---------------- impute: pred[h][w] = MLP(x_emb[h] * y_emb[w]) ----------------
__global__ __launch_bounds__(256) void impute_kernel(
    const float* __restrict__ xe, const float* __restrict__ ye,
    const float* __restrict__ w1, const float* __restrict__ b1,
    const float* __restrict__ w2, const float* __restrict__ b2,
    float* __restrict__ pred)
{
    __shared__ float sw1[64 * 32];
    __shared__ float sb1[32];
    __shared__ float sw2[32];
    __shared__ float sb2;
    for (int i = threadIdx.x; i < 2048; i += 256) sw1[i] = w1[i];
    if (threadIdx.x < 32) { sb1[threadIdx.x] = b1[threadIdx.x]; sw2[threadIdx.x] = w2[threadIdx.x]; }
    if (threadIdx.x == 0) sb2 = b2[0];
    __syncthreads();

    int t = blockIdx.x * 256 + threadIdx.x;
    if (t >= PREDN) return;
    int h = t >> 7, w = t & 127;

    float acc[32];
#pragma unroll
    for (int j = 0; j < 32; ++j) acc[j] = sb1[j];

    const float* xr = xe + h * 64;
    const float* yr = ye + w * 64;
#pragma unroll 4
    for (int e = 0; e < 64; ++e) {
        float p = xr[e] * yr[e];
#pragma unroll
        for (int j = 0; j < 32; ++j) acc[j] = fmaf(p, sw1[e * 32 + j], acc[j]);
    }
    float o = sb2;
#pragma unroll
    for (int j = 0; j < 32; ++j) {
        float a = acc[j];
        float s = a / (1.0f + expf(-a));   // silu
        o = fmaf(s, sw2[j], o);
    }
    pred[t] = o;
}

// ---------------- phase 1: subsampled count histogram -> threshold bucket ----------------
// One block per sample. Subsample: runs of 16 floats (4x float4) every 512 floats
// => M = NPS/32 = 131072 elements per sample.
__global__ __launch_bounds__(256) void phase1_kernel(
    const float* __restrict__ mask, const float* __restrict__ rnd,
    int* __restrict__ bx_out)
{
    __shared__ u32 hist[NB];
    __shared__ u32 lobs;
    __shared__ u32 tcnt[256];
    for (int i = threadIdx.x; i < NB; i += 256) hist[i] = 0u;
    if (threadIdx.x == 0) lobs = 0u;
    __syncthreads();

    const int s = blockIdx.x;
    const float4* m4 = (const float4*)(mask + (size_t)s * NPS);
    const float4* r4 = (const float4*)(rnd  + (size_t)s * NPS);

    u32 myobs = 0;
    for (int i = 0; i < 32; ++i) {
        int r = i * 256 + threadIdx.x;        // run id in [0, 8192)
        int base4 = r * 128;                  // float4 index of run start
        float4 mm[4], rr[4];
#pragma unroll
        for (int q = 0; q < 4; ++q) { mm[q] = m4[base4 + q]; rr[q] = r4[base4 + q]; }
#pragma unroll
        for (int q = 0; q < 4; ++q) {
#pragma unroll
            for (int j = 0; j < 4; ++j) {
                float m = (&mm[q].x)[j];
                if (m != 0.0f) {
                    myobs++;
                    float rm = (&rr[q].x)[j] * m;
                    if (rm > 0.0f) {
                        int b = (int)(rm * (float)NB);
                        b = b < NB ? b : NB - 1;
                        atomicAdd(&hist[b], 1u);
                    }
                }
            }
        }
    }
    atomicAdd(&lobs, myobs);
    __syncthreads();

    {   // per-thread sums of 8 consecutive buckets
        int t = threadIdx.x;
        u32 c = 0;
#pragma unroll
        for (int i = 0; i < NB / 256; ++i) c += hist[t * (NB / 256) + i];
        tcnt[t] = c;
    }
    __syncthreads();

    if (threadIdx.x == 0) {
        const int CPT = NB / 256;
        float ksub = 0.1f * (float)lobs;   // target rank in subsample
        long long cum = 0; int bx = 0; int tx = -1;
        for (int t = 255; t >= 0; --t) {
            if ((float)(cum + (long long)tcnt[t]) >= ksub) { tx = t; break; }
            cum += tcnt[t];
        }
        if (tx < 0) bx = 0;
        else {
            bx = tx * CPT;   // fallback: lowest bucket of chunk
            for (int b = tx * CPT + CPT - 1; b >= tx * CPT; --b) {
                if ((float)(cum + (long long)hist[b]) >= ksub) { bx = b; break; }
                cum += hist[b];
            }
        }
        bx_out[s] = bx;
    }
}

// ---------------- phase 2: streaming classify + register accumulate ----------------
__global__ __launch_bounds__(256) void phase2_kernel(
    const float* __restrict__ data, const float* __restrict__ mask,
    const float* __restrict__ rnd, const float* __restrict__ pred,
    const int* __restrict__ bx_in, u32* __restrict__ acc)
{
    const int s = blockIdx.y;
    const int bx = bx_in[s];
    const int zlo = bx - ZONE < 0 ? 0 : bx - ZONE;
    const int zhi = bx + ZONE > NB - 1 ? NB - 1 : bx + ZONE;

    const int start = blockIdx.x * CHUNK;
    const size_t base = (size_t)s * NPS + start;

    const float4* __restrict__ d4 = (const float4*)(data + base);
    const float4* __restrict__ m4 = (const float4*)(mask + base);
    const float4* __restrict__ r4 = (const float4*)(rnd + base);
    const float4* __restrict__ p4 = (const float4*)pred;   // block spans exactly one pred period

    u32 cobs = 0, cz = 0, chi = 0, cx = 0;
    float sz = 0.0f, shi = 0.0f, sx = 0.0f;

#pragma unroll
    for (int g = 0; g < 4; ++g) {
        const int v0 = g * 1024 + threadIdx.x;
        float4 dd[4], mm[4], rr[4], pp[4];
#pragma unroll
        for (int u = 0; u < 4; ++u) {
            int v = v0 + u * 256;
            dd[u] = d4[v];
            mm[u] = m4[v];
            rr[u] = r4[v];
            pp[u] = p4[v];          // v in [0,4096) == pred float4 index
        }
#pragma unroll
        for (int u = 0; u < 4; ++u) {
#pragma unroll
            for (int j = 0; j < 4; ++j) {
                float m = (&mm[u].x)[j];
                bool obs = (m != 0.0f);
                float rm = (&rr[u].x)[j] * m;
                float resid = (&dd[u].x)[j] - (&pp[u].x)[j];
                float r2 = resid * resid;
                int b = (int)(rm * (float)NB);
                b = b < NB ? b : NB - 1;
                bool z  = obs && (rm <= 0.0f);
                bool hi = obs && (rm > 0.0f) && (b > zhi);
                bool x  = obs && (rm > 0.0f) && (b >= zlo) && (b <= zhi);
                cobs += obs ? 1u : 0u;
                cz   += z   ? 1u : 0u;
                chi  += hi  ? 1u : 0u;
                cx   += x   ? 1u : 0u;
                sz  += z  ? r2 : 0.0f;
                shi += hi ? r2 : 0.0f;
                sx  += x  ? r2 : 0.0f;
            }
        }
    }

    // wave-level shuffle reduction
#pragma unroll
    for (int off = 32; off >= 1; off >>= 1) {
        cobs += __shfl_down(cobs, off, 64);
        cz   += __shfl_down(cz, off, 64);
        chi  += __shfl_down(chi, off, 64);
        cx   += __shfl_down(cx, off, 64);
        sz   += __shfl_down(sz, off, 64);
        shi  += __shfl_down(shi, off, 64);
        sx   += __shfl_down(sx, off, 64);
    }

    __shared__ u32   wc[4][4];
    __shared__ float wsm[4][3];
    const int wave = threadIdx.x >> 6;
    const int lane = threadIdx.x & 63;
    if (lane == 0) {
        wc[wave][0] = cobs; wc[wave][1] = cz; wc[wave][2] = chi; wc[wave][3] = cx;
        wsm[wave][0] = sz; wsm[wave][1] = shi; wsm[wave][2] = sx;
    }
    __syncthreads();
    if (threadIdx.x == 0) {
        u32 C[4] = {0, 0, 0, 0}; float S[3] = {0.f, 0.f, 0.f};
#pragma unroll
        for (int w = 0; w < 4; ++w) {
#pragma unroll
            for (int i = 0; i < 4; ++i) C[i] += wc[w][i];
#pragma unroll
            for (int i = 0; i < 3; ++i) S[i] += wsm[w][i];
        }
        u32* a = acc + s * ACC_STRIDE;
        if (C[0]) atomicAdd(&a[0], C[0]);
        if (C[1]) atomicAdd(&a[1], C[1]);
        if (C[2]) atomicAdd(&a[2], C[2]);
        if (C[3]) atomicAdd(&a[3], C[3]);
        float* fa = (float*)a;
#if defined(__HIP_DEVICE_COMPILE__)
        if (S[0] != 0.f) unsafeAtomicAdd(&fa[4], S[0]);
        if (S[1] != 0.f) unsafeAtomicAdd(&fa[5], S[1]);
        if (S[2] != 0.f) unsafeAtomicAdd(&fa[6], S[2]);
#else
        if (S[0] != 0.f) atomicAdd(&fa[4], S[0]);
        if (S[1] != 0.f) atomicAdd(&fa[5], S[1]);
        if (S[2] != 0.f) atomicAdd(&fa[6], S[2]);
#endif
    }
}

// ---------------- finalize: per-sample interpolation + global ratio ----------------
__global__ void finalize_kernel(const u32* __restrict__ acc, float* __restrict__ out)
{
    if (blockIdx.x == 0 && threadIdx.x == 0) {
        double S = 0.0, C = 0.0;
        for (int s = 0; s < NSAMP; ++s) {
            const u32* a = acc + s * ACC_STRIDE;
            const float* fa = (const float*)a;
            long long nobs = (long long)a[0];
            long long cz   = (long long)a[1];
            long long chi  = (long long)a[2];
            long long cx   = (long long)a[3];
            double sz = fa[4], shi = fa[5], sx = fa[6];
            long long k = (long long)rintf(0.1f * (float)nobs);   // jnp.round semantics
            long long need = k - chi;
            if (need < 0) need = 0;
            if (need > cx) need = cx;
            double frac = cx > 0 ? (double)need / (double)cx : 0.0;
            S += shi + frac * sx + sz;
            C += (double)(chi + need + cz);
        }
        out[0] = (float)(S / (C > 0.0 ? C : 1.0));
    }
}

extern "C" void kernel_launch(void* const* d_in, const int* in_sizes, int n_in,
                              void* d_out, int out_size, void* d_ws, size_t ws_size,
                              hipStream_t stream)
{
    const float* data = (const float*)d_in[0];
    const float* mask = (const float*)d_in[1];
    const float* rnd  = (const float*)d_in[4];
    const float* xe   = (const float*)d_in[5];
    const float* ye   = (const float*)d_in[6];
    const float* w1   = (const float*)d_in[7];
    const float* b1   = (const float*)d_in[8];
    const float* w2   = (const float*)d_in[9];
    const float* b2   = (const float*)d_in[10];
    float* out = (float*)d_out;

    char* ws = (char*)d_ws;
    float* pred = (float*)(ws);                      // 65536 B
    int*   bx   = (int*)(ws + 65536);                // 32 B
    u32*   acc  = (u32*)(ws + 65536 + 64);           // 8 samples * 8 slots * 4B = 256 B

    hipMemsetAsync(ws + 65536, 0, 64 + 256, stream);

    phase1_kernel<<<NSAMP, 256, 0, stream>>>(mask, rnd, bx);
    impute_kernel<<<(PREDN + 255) / 256, 256, 0, stream>>>(xe, ye, w1, b1, w2, b2, pred);

    dim3 grid(BPS, NSAMP);
    phase2_kernel<<<grid, 256, 0, stream>>>(data, mask, rnd, pred, bx, acc);

    finalize_kernel<<<1, 64, 0, stream>>>(acc, out);
}

// Round 4
// 184.801 us; speedup vs baseline: 1.3031x; 1.1646x over previous
//
#include <hip/hip_runtime.h>

typedef unsigned int u32;

#define NPS   (256 * 1 * 128 * 128)   // elements per sample = 4194304
#define NSAMP 8
#define NB    2048                    // threshold-histogram buckets
#define PREDN 16384                   // H*W
#define BPS   256                     // blocks per sample in phase2
#define CHUNK (NPS / BPS)             // 16384 elements per block
#define ZONE  4                       // zone half-width in buckets
#define PBPS  16                      // phase1 blocks per sample

// acc layout per sample (8 u32 slots): 0 cnt_obs, 1 cnt_z, 2 cnt_hi, 3 cnt_x,
//                                      4 sum_z(f32), 5 sum_hi(f32), 6 sum_x(f32), 7 pad
#define ACC_STRIDE 8

// ---------------- impute: pred[h][w] = MLP(x_emb[h] * y_emb[w]) ----------------
__global__ __launch_bounds__(256) void impute_kernel(
    const float* __restrict__ xe, const float* __restrict__ ye,
    const float* __restrict__ w1, const float* __restrict__ b1,
    const float* __restrict__ w2, const float* __restrict__ b2,
    float* __restrict__ pred)
{
    __shared__ float sw1[64 * 32];
    __shared__ float sb1[32];
    __shared__ float sw2[32];
    __shared__ float sb2;
    for (int i = threadIdx.x; i < 2048; i += 256) sw1[i] = w1[i];
    if (threadIdx.x < 32) { sb1[threadIdx.x] = b1[threadIdx.x]; sw2[threadIdx.x] = w2[threadIdx.x]; }
    if (threadIdx.x == 0) sb2 = b2[0];
    __syncthreads();

    int t = blockIdx.x * 256 + threadIdx.x;
    if (t >= PREDN) return;
    int h = t >> 7, w = t & 127;

    float acc[32];
#pragma unroll
    for (int j = 0; j < 32; ++j) acc[j] = sb1[j];

    const float* xr = xe + h * 64;
    const float* yr = ye + w * 64;
#pragma unroll 4
    for (int e = 0; e < 64; ++e) {
        float p = xr[e] * yr[e];
#pragma unroll
        for (int j = 0; j < 32; ++j) acc[j] = fmaf(p, sw1[e * 32 + j], acc[j]);
    }
    float o = sb2;
#pragma unroll
    for (int j = 0; j < 32; ++j) {
        float a = acc[j];
        float s = a / (1.0f + expf(-a));   // silu
        o = fmaf(s, sw2[j], o);
    }
    pred[t] = o;
}

// ---------------- phase 1a: subsampled per-block histogram + global merge ----------------
// Subsample: runs of 16 floats (4x float4) every 512 floats => 8192 runs/sample.
// Grid (PBPS, NSAMP); each block handles 8192/PBPS = 512 runs.
__global__ __launch_bounds__(256) void phase1_hist(
    const float* __restrict__ mask, const float* __restrict__ rnd,
    u32* __restrict__ ghist, u32* __restrict__ gobs)
{
    __shared__ u32 hist[NB];
    __shared__ u32 lobs;
    for (int i = threadIdx.x; i < NB; i += 256) hist[i] = 0u;
    if (threadIdx.x == 0) lobs = 0u;
    __syncthreads();

    const int s = blockIdx.y;
    const float4* m4 = (const float4*)(mask + (size_t)s * NPS);
    const float4* r4 = (const float4*)(rnd  + (size_t)s * NPS);

    u32 myobs = 0;
#pragma unroll
    for (int i = 0; i < 2; ++i) {
        int r = blockIdx.x * 512 + i * 256 + threadIdx.x;   // run id
        int base4 = r * 128;                                // float4 index of run start
        float4 mm[4], rr[4];
#pragma unroll
        for (int q = 0; q < 4; ++q) { mm[q] = m4[base4 + q]; rr[q] = r4[base4 + q]; }
#pragma unroll
        for (int q = 0; q < 4; ++q) {
#pragma unroll
            for (int j = 0; j < 4; ++j) {
                float m = (&mm[q].x)[j];
                if (m != 0.0f) {
                    myobs++;
                    float rm = (&rr[q].x)[j] * m;
                    if (rm > 0.0f) {
                        int b = (int)(rm * (float)NB);
                        b = b < NB ? b : NB - 1;
                        atomicAdd(&hist[b], 1u);
                    }
                }
            }
        }
    }
    atomicAdd(&lobs, myobs);
    __syncthreads();

    u32* gh = ghist + s * NB;
    for (int i = threadIdx.x; i < NB; i += 256) {
        u32 c = hist[i];
        if (c) atomicAdd(&gh[i], c);
    }
    if (threadIdx.x == 0) atomicAdd(&gobs[s], lobs);
}

// ---------------- phase 1b: per-sample threshold bucket from merged histogram ----------------
__global__ __launch_bounds__(256) void phase1_select(
    const u32* __restrict__ ghist, const u32* __restrict__ gobs,
    int* __restrict__ bx_out)
{
    const int s = blockIdx.x;
    __shared__ u32 hist[NB];
    __shared__ u32 tcnt[256];
    const u32* gh = ghist + s * NB;
    for (int i = threadIdx.x; i < NB; i += 256) hist[i] = gh[i];
    __syncthreads();

    {
        int t = threadIdx.x;
        u32 c = 0;
#pragma unroll
        for (int i = 0; i < NB / 256; ++i) c += hist[t * (NB / 256) + i];
        tcnt[t] = c;
    }
    __syncthreads();

    if (threadIdx.x == 0) {
        const int CPT = NB / 256;
        float ksub = 0.1f * (float)gobs[s];
        long long cum = 0; int bx = 0; int tx = -1;
        for (int t = 255; t >= 0; --t) {
            if ((float)(cum + (long long)tcnt[t]) >= ksub) { tx = t; break; }
            cum += tcnt[t];
        }
        if (tx >= 0) {
            bx = tx * CPT;
            for (int b = tx * CPT + CPT - 1; b >= tx * CPT; --b) {
                if ((float)(cum + (long long)hist[b]) >= ksub) { bx = b; break; }
                cum += hist[b];
            }
        }
        bx_out[s] = bx;
    }
}

// ---------------- phase 2: streaming classify, deep register pipeline ----------------
__global__ __launch_bounds__(256) void phase2_kernel(
    const float* __restrict__ data, const float* __restrict__ mask,
    const float* __restrict__ rnd, const float* __restrict__ pred,
    const int* __restrict__ bx_in, u32* __restrict__ acc)
{
    const int s = blockIdx.y;
    const int bx = bx_in[s];
    const int zlo = bx - ZONE < 0 ? 0 : bx - ZONE;
    const int zhi = bx + ZONE > NB - 1 ? NB - 1 : bx + ZONE;
    const float tlo = (float)zlo / (float)NB;
    const float thi = (float)(zhi + 1) / (float)NB;

    const int start = blockIdx.x * CHUNK;
    const size_t base = (size_t)s * NPS + start;

    const float4* __restrict__ d4 = (const float4*)(data + base);
    const float4* __restrict__ m4 = (const float4*)(mask + base);
    const float4* __restrict__ r4 = (const float4*)(rnd + base);
    const float4* __restrict__ p4 = (const float4*)pred;   // block spans exactly one pred period

    const int tid = threadIdx.x;

    u32 cobs = 0, cz = 0, chi = 0, cx = 0;
    float sz = 0.0f, shi = 0.0f, sx = 0.0f;

    // 16 float4 per thread per stream = 8 steps of 2 float4; A/B register sets.
    float4 dA0, dA1, mA0, mA1, rA0, rA1, pA0, pA1;
    float4 dB0, dB1, mB0, mB1, rB0, rB1, pB0, pB1;

#define LOADSET(D0,D1,M0,M1,R0,R1,P0,P1,t) do { \
        int v0_ = (t) * 512 + tid, v1_ = v0_ + 256; \
        D0 = d4[v0_]; D1 = d4[v1_]; \
        M0 = m4[v0_]; M1 = m4[v1_]; \
        R0 = r4[v0_]; R1 = r4[v1_]; \
        P0 = p4[v0_]; P1 = p4[v1_]; \
    } while (0)

#define PROC1(DD,MM,RR,PP) do { \
        _Pragma("unroll") \
        for (int j = 0; j < 4; ++j) { \
            float m_ = (&MM.x)[j]; \
            bool obs_ = (m_ != 0.0f); \
            float rm_ = (&RR.x)[j] * m_; \
            float rs_ = (&DD.x)[j] - (&PP.x)[j]; \
            float r2_ = rs_ * rs_; \
            bool z_  = obs_ && (rm_ <= 0.0f); \
            bool hi_ = obs_ && (rm_ > thi); \
            bool x_  = obs_ && (rm_ > tlo) && (rm_ <= thi) && (rm_ > 0.0f); \
            cobs += obs_ ? 1u : 0u; \
            cz   += z_   ? 1u : 0u; \
            chi  += hi_  ? 1u : 0u; \
            cx   += x_   ? 1u : 0u; \
            sz  += z_  ? r2_ : 0.0f; \
            shi += hi_ ? r2_ : 0.0f; \
            sx  += x_  ? r2_ : 0.0f; \
        } \
    } while (0)

#define PROCA do { PROC1(dA0,mA0,rA0,pA0); PROC1(dA1,mA1,rA1,pA1); } while (0)
#define PROCB do { PROC1(dB0,mB0,rB0,pB0); PROC1(dB1,mB1,rB1,pB1); } while (0)
#define LOADA(t) LOADSET(dA0,dA1,mA0,mA1,rA0,rA1,pA0,pA1,t)
#define LOADB(t) LOADSET(dB0,dB1,mB0,mB1,rB0,rB1,pB0,pB1,t)
#define SB __builtin_amdgcn_sched_barrier(0)

    LOADA(0); SB;
    LOADB(1); SB;
    PROCA;  LOADA(2); SB;
    PROCB;  LOADB(3); SB;
    PROCA;  LOADA(4); SB;
    PROCB;  LOADB(5); SB;
    PROCA;  LOADA(6); SB;
    PROCB;  LOADB(7); SB;
    PROCA;
    PROCB;

#undef LOADSET
#undef PROC1
#undef PROCA
#undef PROCB
#undef LOADA
#undef LOADB
#undef SB

    // wave-level shuffle reduction
#pragma unroll
    for (int off = 32; off >= 1; off >>= 1) {
        cobs += __shfl_down(cobs, off, 64);
        cz   += __shfl_down(cz, off, 64);
        chi  += __shfl_down(chi, off, 64);
        cx   += __shfl_down(cx, off, 64);
        sz   += __shfl_down(sz, off, 64);
        shi  += __shfl_down(shi, off, 64);
        sx   += __shfl_down(sx, off, 64);
    }

    __shared__ u32   wc[4][4];
    __shared__ float wsm[4][3];
    const int wave = threadIdx.x >> 6;
    const int lane = threadIdx.x & 63;
    if (lane == 0) {
        wc[wave][0] = cobs; wc[wave][1] = cz; wc[wave][2] = chi; wc[wave][3] = cx;
        wsm[wave][0] = sz; wsm[wave][1] = shi; wsm[wave][2] = sx;
    }
    __syncthreads();
    if (threadIdx.x == 0) {
        u32 C[4] = {0, 0, 0, 0}; float S[3] = {0.f, 0.f, 0.f};
#pragma unroll
        for (int w = 0; w < 4; ++w) {
#pragma unroll
            for (int i = 0; i < 4; ++i) C[i] += wc[w][i];
#pragma unroll
            for (int i = 0; i < 3; ++i) S[i] += wsm[w][i];
        }
        u32* a = acc + s * ACC_STRIDE;
        if (C[0]) atomicAdd(&a[0], C[0]);
        if (C[1]) atomicAdd(&a[1], C[1]);
        if (C[2]) atomicAdd(&a[2], C[2]);
        if (C[3]) atomicAdd(&a[3], C[3]);
        float* fa = (float*)a;
#if defined(__HIP_DEVICE_COMPILE__)
        if (S[0] != 0.f) unsafeAtomicAdd(&fa[4], S[0]);
        if (S[1] != 0.f) unsafeAtomicAdd(&fa[5], S[1]);
        if (S[2] != 0.f) unsafeAtomicAdd(&fa[6], S[2]);
#else
        if (S[0] != 0.f) atomicAdd(&fa[4], S[0]);
        if (S[1] != 0.f) atomicAdd(&fa[5], S[1]);
        if (S[2] != 0.f) atomicAdd(&fa[6], S[2]);
#endif
    }
}

// ---------------- finalize: per-sample interpolation + global ratio ----------------
__global__ void finalize_kernel(const u32* __restrict__ acc, float* __restrict__ out)
{
    if (blockIdx.x == 0 && threadIdx.x == 0) {
        double S = 0.0, C = 0.0;
        for (int s = 0; s < NSAMP; ++s) {
            const u32* a = acc + s * ACC_STRIDE;
            const float* fa = (const float*)a;
            long long nobs = (long long)a[0];
            long long cz   = (long long)a[1];
            long long chi  = (long long)a[2];
            long long cx   = (long long)a[3];
            double sz = fa[4], shi = fa[5], sx = fa[6];
            long long k = (long long)rintf(0.1f * (float)nobs);   // jnp.round semantics
            long long need = k - chi;
            if (need < 0) need = 0;
            if (need > cx) need = cx;
            double frac = cx > 0 ? (double)need / (double)cx : 0.0;
            S += shi + frac * sx + sz;
            C += (double)(chi + need + cz);
        }
        out[0] = (float)(S / (C > 0.0 ? C : 1.0));
    }
}

extern "C" void kernel_launch(void* const* d_in, const int* in_sizes, int n_in,
                              void* d_out, int out_size, void* d_ws, size_t ws_size,
                              hipStream_t stream)
{
    const float* data = (const float*)d_in[0];
    const float* mask = (const float*)d_in[1];
    const float* rnd  = (const float*)d_in[4];
    const float* xe   = (const float*)d_in[5];
    const float* ye   = (const float*)d_in[6];
    const float* w1   = (const float*)d_in[7];
    const float* b1   = (const float*)d_in[8];
    const float* w2   = (const float*)d_in[9];
    const float* b2   = (const float*)d_in[10];
    float* out = (float*)d_out;

    char* ws = (char*)d_ws;
    float* pred  = (float*)(ws);               // 65536 B
    u32*   ghist = (u32*)(ws + 65536);         // 8*2048*4 = 65536 B
    u32*   gobs  = (u32*)(ws + 131072);        // 32 B
    int*   bx    = (int*)(ws + 131104);        // 32 B
    u32*   acc   = (u32*)(ws + 131136);        // 256 B

    // zero ghist + gobs + bx + acc
    hipMemsetAsync(ws + 65536, 0, 65536 + 32 + 32 + 256, stream);

    dim3 g1(PBPS, NSAMP);
    phase1_hist<<<g1, 256, 0, stream>>>(mask, rnd, ghist, gobs);
    phase1_select<<<NSAMP, 256, 0, stream>>>(ghist, gobs, bx);
    impute_kernel<<<(PREDN + 255) / 256, 256, 0, stream>>>(xe, ye, w1, b1, w2, b2, pred);

    dim3 g2(BPS, NSAMP);
    phase2_kernel<<<g2, 256, 0, stream>>>(data, mask, rnd, pred, bx, acc);

    finalize_kernel<<<1, 64, 0, stream>>>(acc, out);
}